// Round 15
// baseline (72.729 us; speedup 1.0000x reference)
//
#include <hip/hip_runtime.h>
#include <cstdint>
#include <cstddef>

#define BB 32
#define NN 4096
#define DD 256
#define KK 16

constexpr int TILE  = 64;             // compacted slots per block
constexpr int TPBAT = NN / TILE;      // 64 tiles per batch (max)
constexpr int TILES = BB * TPBAT;     // 2048
constexpr float FEPS = 1e-12f;

__device__ __forceinline__ float dot4(float4 a, float4 b) {
  return a.x*b.x + a.y*b.y + a.z*b.z + a.w*b.w;
}
__device__ __forceinline__ float4 f4add(float4 a, float4 b) {
  return make_float4(a.x+b.x, a.y+b.y, a.z+b.z, a.w+b.w);
}
__device__ __forceinline__ float4 f4fma(float s, float4 x, float4 a) {
  a.x += s*x.x; a.y += s*x.y; a.z += s*x.z; a.w += s*x.w; return a;
}

// ---------------------------------------------------------------------------
// Compact: per batch, clist[b][j] = j-th unmasked token index; ccount[b] = n.
// Deterministic ballot + prefix (no atomics). 32 blocks x 256 threads.
// ---------------------------------------------------------------------------
__global__ __launch_bounds__(256) void compact_kernel(
    const int* __restrict__ mask, int* __restrict__ clist,
    int* __restrict__ ccount)
{
  const int b    = blockIdx.x;
  const int tid  = threadIdx.x;
  const int lane = tid & 63;
  const int wave = tid >> 6;
  const int* mb  = mask + (size_t)b * NN;
  __shared__ int wsum[4];

  int total = 0;
#pragma unroll 1
  for (int g = 0; g < 16; ++g) {
    const int m = mb[wave * 1024 + g * 64 + lane] != 0;
    total += (int)__popcll(__ballot(m));
  }
  if (lane == 0) wsum[wave] = total;
  __syncthreads();

  int run = 0;
  for (int w2 = 0; w2 < wave; ++w2) run += wsum[w2];
#pragma unroll 1
  for (int g = 0; g < 16; ++g) {
    const int tokg = wave * 1024 + g * 64 + lane;
    const int m = mb[tokg] != 0;
    const unsigned long long bits = __ballot(m);
    if (m) {
      const unsigned long long below = bits & ((1ull << lane) - 1ull);
      clist[(size_t)b * NN + run + (int)__popcll(below)] = tokg;
    }
    run += (int)__popcll(bits);
  }
  if (tid == 0) ccount[b] = wsum[0] + wsum[1] + wsum[2] + wsum[3];
}

// ---------------------------------------------------------------------------
// Fused kernel (r14 structure on globally-compacted tokens): block (b,t)
// handles compacted slots [64t, 64t+64); empty blocks exit immediately.
// Phase A: thread = (slot, k-quad); staged 16-dim LDS chunks (dbuf, pad4->5).
// Phase B: wave = k-quad over lcnt compacted tokens (rows via cmap, L1/L2).
// ---------------------------------------------------------------------------
__global__ __launch_bounds__(256, 8) void fused_kernel(
    const float* __restrict__ x, const int* __restrict__ clist,
    const int* __restrict__ ccount, const float* __restrict__ W,
    const float* __restrict__ bias, float* __restrict__ outv,
    float* __restrict__ outs, int partial_mode)
{
  __shared__ float4 xs4[2][TILE * 5];   // 10 KB dbuf staging (pad 4->5)
  __shared__ float  al[TILE * KK];      // 4 KB assigns
  __shared__ float  psum[TILE][4];      // 1 KB exp-sum partials
  __shared__ float  asacc[KK];          // assign-sums
  __shared__ int    cmap[TILE];         // slot -> original token

  const int tid  = threadIdx.x;
  const int lane = tid & 63;
  const int wave = tid >> 6;
  const int tok  = tid & (TILE - 1);    // Phase-A slot
  const int kg   = __builtin_amdgcn_readfirstlane(wave);   // k-quad layer

  const int tile = blockIdx.x;
  const int b    = tile >> 6;           // / TPBAT
  const int t    = tile & (TPBAT - 1);
  const int cnt  = ccount[b];
  if (t * 64 >= cnt) return;            // block-uniform early exit
  const int lcnt = min(64, cnt - t * 64);

  const float4* xb4 = reinterpret_cast<const float4*>(x + (size_t)b * NN * DD);

  if (tid < TILE)
    cmap[tid] = (tid < lcnt) ? clist[(size_t)b * NN + t * 64 + tid] : 0;
  __syncthreads();

  // ---------------- Phase A: 4 logits per thread, dbuf staging ------------
  float part[4];
#pragma unroll
  for (int q = 0; q < 4; ++q) part[q] = bias[kg * 4 + q];

  const int st = tid >> 2;              // staging slot (0..63)
  const int sj = tid & 3;               // staging float4 col within chunk
  const int sact = st < lcnt;
  const int srow = sact ? cmap[st] : 0;

  // prologue: stage chunk 0 into buffer 0 (active slots only)
  if (sact) {
    const float4 p0 = xb4[(size_t)srow * 64 + sj];
    xs4[0][st * 5 + sj] = p0;
  }

#pragma unroll 1
  for (int c = 0; c < 16; ++c) {        // 16 chunks of 16 dims
    __syncthreads();
    const int cur = c & 1;

    float4 nxt;
    if (c < 15 && sact)
      nxt = xb4[(size_t)srow * 64 + (c + 1) * 4 + sj];

#pragma unroll
    for (int j = 0; j < 4; ++j) {
      const float4 xv = xs4[cur][tok * 5 + j];
      const float* Wc = W + c * 16 + j * 4;
#pragma unroll
      for (int q = 0; q < 4; ++q) {
        const float4 wv = *reinterpret_cast<const float4*>(Wc + (kg * 4 + q) * DD);
        part[q] += dot4(xv, wv);
      }
    }

    if (c < 15 && sact)
      xs4[cur ^ 1][st * 5 + sj] = nxt;
  }

  const int act = (tok < lcnt);

  // masked softmax across the 4 k-quad layers via psum exchange
  float e[4], pexp = 0.f;
#pragma unroll
  for (int q = 0; q < 4; ++q) {
    const float ev = __expf(part[q]);
    e[q] = act ? ev : 0.0f;
    pexp += e[q];
  }
  psum[tok][kg] = pexp;
  __syncthreads();
  float a[4];
  {
    float denom = 0.f;
#pragma unroll
    for (int g = 0; g < 4; ++g) denom += psum[tok][g];
    const float r = act ? (1.0f / denom) : 0.0f;
#pragma unroll
    for (int q = 0; q < 4; ++q) a[q] = e[q] * r;
    *reinterpret_cast<float4*>(&al[tok * KK + kg * 4]) =
        make_float4(a[0], a[1], a[2], a[3]);
  }

  // asum: butterfly over 64 lanes (zeros for inactive slots)
  {
    float red[4];
#pragma unroll
    for (int q = 0; q < 4; ++q) red[q] = a[q];
#pragma unroll
    for (int off = 32; off >= 1; off >>= 1)
#pragma unroll
      for (int q = 0; q < 4; ++q) red[q] += __shfl_xor(red[q], off);
    if (lane == 0)
#pragma unroll
      for (int q = 0; q < 4; ++q) asacc[kg * 4 + q] = red[q];
  }
  __syncthreads();

  // ------ Phase B: wave = k-quad, sweep the lcnt compacted tokens ---------
  float4 acc0 = make_float4(0.f,0.f,0.f,0.f);
  float4 acc1 = make_float4(0.f,0.f,0.f,0.f);
  float4 acc2 = make_float4(0.f,0.f,0.f,0.f);
  float4 acc3 = make_float4(0.f,0.f,0.f,0.f);

  const float4* xw = xb4 + lane;        // lane owns dims 4*lane..4*lane+3
  const int kq4 = 4 * wave;

#pragma unroll 4
  for (int tt = 0; tt < lcnt; ++tt) {
    const int tr = cmap[tt];
    const float4 xv = xw[(size_t)tr * 64];
    const float4 av = *reinterpret_cast<const float4*>(&al[tt * KK + kq4]);
    acc0 = f4fma(av.x, xv, acc0);
    acc1 = f4fma(av.y, xv, acc1);
    acc2 = f4fma(av.z, xv, acc2);
    acc3 = f4fma(av.w, xv, acc3);
  }

  // ------------- output ----------------------------------------------------
  const int kq = wave * 4;
  if (partial_mode) {
    float4* dst = reinterpret_cast<float4*>(outv + (size_t)tile * KK * DD);
    dst[(kq + 0) * 64 + lane] = acc0;
    dst[(kq + 1) * 64 + lane] = acc1;
    dst[(kq + 2) * 64 + lane] = acc2;
    dst[(kq + 3) * 64 + lane] = acc3;
    if (tid < KK) outs[tile * KK + tid] = asacc[tid];
  } else {
    float* vb = outv + (size_t)b * KK * DD;
    const float4 aa4[4] = {acc0, acc1, acc2, acc3};
#pragma unroll
    for (int i = 0; i < 4; ++i) {
      float* p = vb + (kq + i) * DD + 4 * lane;
      atomicAdd(p + 0, aa4[i].x);
      atomicAdd(p + 1, aa4[i].y);
      atomicAdd(p + 2, aa4[i].z);
      atomicAdd(p + 3, aa4[i].w);
    }
    if (tid < KK) atomicAdd(&outs[b * KK + tid], asacc[tid]);
  }
}

// ---------------------------------------------------------------------------
// Finalize A (BB*KK blocks x 256 thr): block = (b,k). Sums only the slices
// that were actually written: nslice = ceil(ccount[b]/64) (or fixed).
// ---------------------------------------------------------------------------
__global__ __launch_bounds__(256) void finalizeA_kernel(
    const float* __restrict__ pv, const float* __restrict__ ps,
    const float* __restrict__ cent, float* __restrict__ vtmp,
    float* __restrict__ ssbuf, const int* __restrict__ ccount,
    int nslice_fixed)
{
  const int blk = blockIdx.x;
  const int b   = blk >> 4;
  const int k   = blk & 15;
  const int tid = threadIdx.x;
  const int sg  = tid >> 6;           // slice group 0..3
  const int ld  = tid & 63;           // float4 dim index

  const int nslice = ccount ? min(TPBAT, (ccount[b] + 63) >> 6) : nslice_fixed;

  __shared__ float4 cmbA[3][64];

  float pval = 0.f;
  for (int s = ld; s < nslice; s += 64)
    pval += ps[(size_t)(b * TPBAT + s) * KK + k];
#pragma unroll
  for (int off = 32; off >= 1; off >>= 1) pval += __shfl_xor(pval, off);
  const float ssum = pval;

  const float4* pv4 = reinterpret_cast<const float4*>(pv);
  const size_t base = ((size_t)b * TPBAT * KK + k) * 64 + ld;
  float4 a0 = make_float4(0.f,0.f,0.f,0.f), a1 = a0, a2 = a0, a3 = a0;
  int s = sg;
  for (; s + 12 < nslice; s += 16) {
    a0 = f4add(a0, pv4[base + (size_t)(s     ) * (KK * 64)]);
    a1 = f4add(a1, pv4[base + (size_t)(s +  4) * (KK * 64)]);
    a2 = f4add(a2, pv4[base + (size_t)(s +  8) * (KK * 64)]);
    a3 = f4add(a3, pv4[base + (size_t)(s + 12) * (KK * 64)]);
  }
  for (; s < nslice; s += 4)
    a0 = f4add(a0, pv4[base + (size_t)s * (KK * 64)]);
  float4 tot = f4add(f4add(a0, a1), f4add(a2, a3));

  if (sg > 0) cmbA[sg - 1][ld] = tot;
  __syncthreads();

  if (sg == 0) {
    tot = f4add(tot, f4add(cmbA[0][ld], f4add(cmbA[1][ld], cmbA[2][ld])));
    const float4 cv = reinterpret_cast<const float4*>(cent)[k * 64 + ld];
    float4 v;
    v.x = tot.x - ssum * cv.x;
    v.y = tot.y - ssum * cv.y;
    v.z = tot.z - ssum * cv.z;
    v.w = tot.w - ssum * cv.w;
    reinterpret_cast<float4*>(vtmp)[((size_t)b * KK + k) * 64 + ld] = v;
    float p = dot4(v, v);
#pragma unroll
    for (int off = 32; off >= 1; off >>= 1) p += __shfl_xor(p, off);
    if (ld == 0) ssbuf[blk] = p;
  }
}

// ---------------------------------------------------------------------------
// Finalize B (BB blocks x 1024 thr): intra-cluster + global L2 normalize.
// ---------------------------------------------------------------------------
__global__ __launch_bounds__(1024) void finalizeB_kernel(
    const float* __restrict__ vtmp, const float* __restrict__ ssbuf,
    float* __restrict__ out)
{
  const int b    = blockIdx.x;
  const int tid  = threadIdx.x;
  const int d    = tid & 255;
  const int kq   = tid >> 8;
  const int lane = tid & 63;
  const int w    = tid >> 6;

  __shared__ float redB[16];
  __shared__ float gsh;

  float u[4];
  float p2 = 0.f;
#pragma unroll
  for (int kk = 0; kk < 4; ++kk) {
    const int k = kq * 4 + kk;
    const float rk = 1.0f / fmaxf(sqrtf(ssbuf[b * KK + k]), FEPS);
    u[kk] = vtmp[((size_t)b * KK + k) * DD + d] * rk;
    p2 += u[kk] * u[kk];
  }
#pragma unroll
  for (int off = 32; off >= 1; off >>= 1) p2 += __shfl_xor(p2, off);
  if (lane == 0) redB[w] = p2;
  __syncthreads();

  if (tid == 0) {
    float g = 0.f;
#pragma unroll
    for (int i = 0; i < 16; ++i) g += redB[i];
    gsh = 1.0f / fmaxf(sqrtf(g), FEPS);
  }
  __syncthreads();

  const float g = gsh;
#pragma unroll
  for (int kk = 0; kk < 4; ++kk) {
    const int k = kq * 4 + kk;
    out[(size_t)b * KK * DD + k * DD + d] = u[kk] * g;
  }
}

extern "C" void kernel_launch(void* const* d_in, const int* in_sizes, int n_in,
                              void* d_out, int out_size, void* d_ws, size_t ws_size,
                              hipStream_t stream) {
  const float* x    = (const float*)d_in[0];
  const int*   mask = (const int*)d_in[1];
  const float* W    = (const float*)d_in[2];
  const float* bias = (const float*)d_in[3];
  const float* cent = (const float*)d_in[4];
  float* out = (float*)d_out;

  const size_t pvN   = (size_t)TILES * KK * DD;
  const size_t psN   = (size_t)TILES * KK;
  const size_t vtmpN = (size_t)BB * KK * DD;
  const size_t ssN   = (size_t)BB * KK;
  const size_t clN   = (size_t)BB * NN;     // clist ints
  const size_t ccN   = (size_t)BB;          // ccount ints

  const size_t needP = (pvN + psN + vtmpN + ssN) * sizeof(float)
                     + (clN + ccN) * sizeof(int);
  const size_t needA = (vtmpN + ssN + vtmpN + ssN) * sizeof(float)
                     + (clN + ccN) * sizeof(int);

  if (ws_size >= needP) {
    float* pv    = (float*)d_ws;
    float* ps    = pv + pvN;
    float* vtmp  = ps + psN;
    float* ssbuf = vtmp + vtmpN;
    int*   clist = (int*)(ssbuf + ssN);
    int*   ccnt  = clist + clN;
    compact_kernel<<<BB, 256, 0, stream>>>(mask, clist, ccnt);
    fused_kernel<<<TILES, 256, 0, stream>>>(x, clist, ccnt, W, bias, pv, ps, 1);
    finalizeA_kernel<<<BB * KK, 256, 0, stream>>>(pv, ps, cent, vtmp, ssbuf, ccnt, 0);
    finalizeB_kernel<<<BB, 1024, 0, stream>>>(vtmp, ssbuf, out);
  } else {
    (void)needA;
    float* vacc  = (float*)d_ws;              // [BB][KK][DD]
    float* sacc  = vacc + vtmpN;              // [BB][KK]
    float* vtmp  = sacc + ssN;
    float* ssbuf = vtmp + vtmpN;
    int*   clist = (int*)(ssbuf + ssN);
    int*   ccnt  = clist + clN;
    hipMemsetAsync(d_ws, 0, (vtmpN + ssN) * sizeof(float), stream);
    compact_kernel<<<BB, 256, 0, stream>>>(mask, clist, ccnt);
    fused_kernel<<<TILES, 256, 0, stream>>>(x, clist, ccnt, W, bias, vacc, sacc, 0);
    finalizeA_kernel<<<BB * KK, 256, 0, stream>>>(vacc, sacc, cent, vtmp, ssbuf, nullptr, 1);
    finalizeB_kernel<<<BB, 1024, 0, stream>>>(vtmp, ssbuf, out);
  }
}

// Round 16
// 67.699 us; speedup vs baseline: 1.0743x; 1.0743x over previous
//
#include <hip/hip_runtime.h>
#include <cstdint>
#include <cstddef>

#define BB 32
#define NN 4096
#define DD 256
#define KK 16

constexpr int TILE  = 64;             // compacted slots per block
constexpr int TPBAT = NN / TILE;      // 64 tiles per batch (max)
constexpr int TILES = BB * TPBAT;     // 2048
constexpr float FEPS = 1e-12f;

__device__ __forceinline__ float dot4(float4 a, float4 b) {
  return a.x*b.x + a.y*b.y + a.z*b.z + a.w*b.w;
}
__device__ __forceinline__ float4 f4add(float4 a, float4 b) {
  return make_float4(a.x+b.x, a.y+b.y, a.z+b.z, a.w+b.w);
}
__device__ __forceinline__ float4 f4fma(float s, float4 x, float4 a) {
  a.x += s*x.x; a.y += s*x.y; a.z += s*x.z; a.w += s*x.w; return a;
}

// ---------------------------------------------------------------------------
// Compact (low-latency): 32 blocks x 1024 thr; wave = 256 contiguous tokens
// = 4 ballot groups. All loads issued upfront; mask kept in registers for the
// write pass; one LDS prefix + barrier. Deterministic (no atomics).
// ---------------------------------------------------------------------------
__global__ __launch_bounds__(1024) void compact_kernel(
    const int* __restrict__ mask, int* __restrict__ clist,
    int* __restrict__ ccount)
{
  const int b    = blockIdx.x;
  const int tid  = threadIdx.x;
  const int lane = tid & 63;
  const int wave = tid >> 6;            // 0..15
  const int* mb  = mask + (size_t)b * NN;
  __shared__ int wsum[16];

  int m[4];
#pragma unroll
  for (int g = 0; g < 4; ++g)
    m[g] = mb[wave * 256 + g * 64 + lane];

  unsigned long long bits[4];
  int cnt[4];
  int total = 0;
#pragma unroll
  for (int g = 0; g < 4; ++g) {
    bits[g] = __ballot(m[g] != 0);
    cnt[g]  = (int)__popcll(bits[g]);
    total  += cnt[g];
  }
  if (lane == 0) wsum[wave] = total;
  __syncthreads();

  int run = 0;
  for (int w2 = 0; w2 < wave; ++w2) run += wsum[w2];

#pragma unroll
  for (int g = 0; g < 4; ++g) {
    if (m[g]) {
      const unsigned long long below = bits[g] & ((1ull << lane) - 1ull);
      clist[(size_t)b * NN + run + (int)__popcll(below)] =
          wave * 256 + g * 64 + lane;
    }
    run += cnt[g];
  }
  if (tid == 0) {
    int t = 0;
#pragma unroll
    for (int i = 0; i < 16; ++i) t += wsum[i];
    ccount[b] = t;
  }
}

// ---------------------------------------------------------------------------
// Fused kernel (r15 structure): block (b,t) handles compacted slots
// [64t, 64t+64); empty blocks exit immediately.
// Phase A: thread = (slot, k-quad); staged 16-dim LDS chunks (dbuf, pad4->5).
// Phase B: wave = k-quad over lcnt compacted tokens (rows via cmap, L1/L2).
// ---------------------------------------------------------------------------
__global__ __launch_bounds__(256, 8) void fused_kernel(
    const float* __restrict__ x, const int* __restrict__ clist,
    const int* __restrict__ ccount, const float* __restrict__ W,
    const float* __restrict__ bias, float* __restrict__ outv,
    float* __restrict__ outs, int partial_mode)
{
  __shared__ float4 xs4[2][TILE * 5];   // 10 KB dbuf staging (pad 4->5)
  __shared__ float  al[TILE * KK];      // 4 KB assigns
  __shared__ float  psum[TILE][4];      // 1 KB exp-sum partials
  __shared__ float  asacc[KK];          // assign-sums
  __shared__ int    cmap[TILE];         // slot -> original token

  const int tid  = threadIdx.x;
  const int lane = tid & 63;
  const int wave = tid >> 6;
  const int tok  = tid & (TILE - 1);    // Phase-A slot
  const int kg   = __builtin_amdgcn_readfirstlane(wave);   // k-quad layer

  const int tile = blockIdx.x;
  const int b    = tile >> 6;           // / TPBAT
  const int t    = tile & (TPBAT - 1);
  const int cnt  = ccount[b];
  if (t * 64 >= cnt) return;            // block-uniform early exit
  const int lcnt = min(64, cnt - t * 64);

  const float4* xb4 = reinterpret_cast<const float4*>(x + (size_t)b * NN * DD);

  if (tid < TILE)
    cmap[tid] = (tid < lcnt) ? clist[(size_t)b * NN + t * 64 + tid] : 0;
  __syncthreads();

  // ---------------- Phase A: 4 logits per thread, dbuf staging ------------
  float part[4];
#pragma unroll
  for (int q = 0; q < 4; ++q) part[q] = bias[kg * 4 + q];

  const int st = tid >> 2;              // staging slot (0..63)
  const int sj = tid & 3;               // staging float4 col within chunk
  const int sact = st < lcnt;
  const int srow = sact ? cmap[st] : 0;

  // prologue: stage chunk 0 into buffer 0 (active slots only)
  if (sact) {
    const float4 p0 = xb4[(size_t)srow * 64 + sj];
    xs4[0][st * 5 + sj] = p0;
  }

#pragma unroll 1
  for (int c = 0; c < 16; ++c) {        // 16 chunks of 16 dims
    __syncthreads();
    const int cur = c & 1;

    float4 nxt;
    if (c < 15 && sact)
      nxt = xb4[(size_t)srow * 64 + (c + 1) * 4 + sj];

#pragma unroll
    for (int j = 0; j < 4; ++j) {
      const float4 xv = xs4[cur][tok * 5 + j];
      const float* Wc = W + c * 16 + j * 4;
#pragma unroll
      for (int q = 0; q < 4; ++q) {
        const float4 wv = *reinterpret_cast<const float4*>(Wc + (kg * 4 + q) * DD);
        part[q] += dot4(xv, wv);
      }
    }

    if (c < 15 && sact)
      xs4[cur ^ 1][st * 5 + sj] = nxt;
  }

  const int act = (tok < lcnt);

  // masked softmax across the 4 k-quad layers via psum exchange
  float e[4], pexp = 0.f;
#pragma unroll
  for (int q = 0; q < 4; ++q) {
    const float ev = __expf(part[q]);
    e[q] = act ? ev : 0.0f;
    pexp += e[q];
  }
  psum[tok][kg] = pexp;
  __syncthreads();
  float a[4];
  {
    float denom = 0.f;
#pragma unroll
    for (int g = 0; g < 4; ++g) denom += psum[tok][g];
    const float r = act ? (1.0f / denom) : 0.0f;
#pragma unroll
    for (int q = 0; q < 4; ++q) a[q] = e[q] * r;
    *reinterpret_cast<float4*>(&al[tok * KK + kg * 4]) =
        make_float4(a[0], a[1], a[2], a[3]);
  }

  // asum: butterfly over 64 lanes (zeros for inactive slots)
  {
    float red[4];
#pragma unroll
    for (int q = 0; q < 4; ++q) red[q] = a[q];
#pragma unroll
    for (int off = 32; off >= 1; off >>= 1)
#pragma unroll
      for (int q = 0; q < 4; ++q) red[q] += __shfl_xor(red[q], off);
    if (lane == 0)
#pragma unroll
      for (int q = 0; q < 4; ++q) asacc[kg * 4 + q] = red[q];
  }
  __syncthreads();

  // ------ Phase B: wave = k-quad, sweep the lcnt compacted tokens ---------
  float4 acc0 = make_float4(0.f,0.f,0.f,0.f);
  float4 acc1 = make_float4(0.f,0.f,0.f,0.f);
  float4 acc2 = make_float4(0.f,0.f,0.f,0.f);
  float4 acc3 = make_float4(0.f,0.f,0.f,0.f);

  const float4* xw = xb4 + lane;        // lane owns dims 4*lane..4*lane+3
  const int kq4 = 4 * wave;

#pragma unroll 4
  for (int tt = 0; tt < lcnt; ++tt) {
    const int tr = cmap[tt];
    const float4 xv = xw[(size_t)tr * 64];
    const float4 av = *reinterpret_cast<const float4*>(&al[tt * KK + kq4]);
    acc0 = f4fma(av.x, xv, acc0);
    acc1 = f4fma(av.y, xv, acc1);
    acc2 = f4fma(av.z, xv, acc2);
    acc3 = f4fma(av.w, xv, acc3);
  }

  // ------------- output ----------------------------------------------------
  const int kq = wave * 4;
  if (partial_mode) {
    float4* dst = reinterpret_cast<float4*>(outv + (size_t)tile * KK * DD);
    dst[(kq + 0) * 64 + lane] = acc0;
    dst[(kq + 1) * 64 + lane] = acc1;
    dst[(kq + 2) * 64 + lane] = acc2;
    dst[(kq + 3) * 64 + lane] = acc3;
    if (tid < KK) outs[tile * KK + tid] = asacc[tid];
  } else {
    float* vb = outv + (size_t)b * KK * DD;
    const float4 aa4[4] = {acc0, acc1, acc2, acc3};
#pragma unroll
    for (int i = 0; i < 4; ++i) {
      float* p = vb + (kq + i) * DD + 4 * lane;
      atomicAdd(p + 0, aa4[i].x);
      atomicAdd(p + 1, aa4[i].y);
      atomicAdd(p + 2, aa4[i].z);
      atomicAdd(p + 3, aa4[i].w);
    }
    if (tid < KK) atomicAdd(&outs[b * KK + tid], asacc[tid]);
  }
}

// ---------------------------------------------------------------------------
// Finalize A (BB*KK blocks x 256 thr): block = (b,k). Sums only the slices
// that were actually written: nslice = ceil(ccount[b]/64) (or fixed).
// ---------------------------------------------------------------------------
__global__ __launch_bounds__(256) void finalizeA_kernel(
    const float* __restrict__ pv, const float* __restrict__ ps,
    const float* __restrict__ cent, float* __restrict__ vtmp,
    float* __restrict__ ssbuf, const int* __restrict__ ccount,
    int nslice_fixed)
{
  const int blk = blockIdx.x;
  const int b   = blk >> 4;
  const int k   = blk & 15;
  const int tid = threadIdx.x;
  const int sg  = tid >> 6;           // slice group 0..3
  const int ld  = tid & 63;           // float4 dim index

  const int nslice = ccount ? min(TPBAT, (ccount[b] + 63) >> 6) : nslice_fixed;

  __shared__ float4 cmbA[3][64];

  float pval = 0.f;
  for (int s = ld; s < nslice; s += 64)
    pval += ps[(size_t)(b * TPBAT + s) * KK + k];
#pragma unroll
  for (int off = 32; off >= 1; off >>= 1) pval += __shfl_xor(pval, off);
  const float ssum = pval;

  const float4* pv4 = reinterpret_cast<const float4*>(pv);
  const size_t base = ((size_t)b * TPBAT * KK + k) * 64 + ld;
  float4 a0 = make_float4(0.f,0.f,0.f,0.f), a1 = a0, a2 = a0, a3 = a0;
  int s = sg;
  for (; s + 12 < nslice; s += 16) {
    a0 = f4add(a0, pv4[base + (size_t)(s     ) * (KK * 64)]);
    a1 = f4add(a1, pv4[base + (size_t)(s +  4) * (KK * 64)]);
    a2 = f4add(a2, pv4[base + (size_t)(s +  8) * (KK * 64)]);
    a3 = f4add(a3, pv4[base + (size_t)(s + 12) * (KK * 64)]);
  }
  for (; s < nslice; s += 4)
    a0 = f4add(a0, pv4[base + (size_t)s * (KK * 64)]);
  float4 tot = f4add(f4add(a0, a1), f4add(a2, a3));

  if (sg > 0) cmbA[sg - 1][ld] = tot;
  __syncthreads();

  if (sg == 0) {
    tot = f4add(tot, f4add(cmbA[0][ld], f4add(cmbA[1][ld], cmbA[2][ld])));
    const float4 cv = reinterpret_cast<const float4*>(cent)[k * 64 + ld];
    float4 v;
    v.x = tot.x - ssum * cv.x;
    v.y = tot.y - ssum * cv.y;
    v.z = tot.z - ssum * cv.z;
    v.w = tot.w - ssum * cv.w;
    reinterpret_cast<float4*>(vtmp)[((size_t)b * KK + k) * 64 + ld] = v;
    float p = dot4(v, v);
#pragma unroll
    for (int off = 32; off >= 1; off >>= 1) p += __shfl_xor(p, off);
    if (ld == 0) ssbuf[blk] = p;
  }
}

// ---------------------------------------------------------------------------
// Finalize B (BB blocks x 1024 thr): intra-cluster + global L2 normalize.
// ---------------------------------------------------------------------------
__global__ __launch_bounds__(1024) void finalizeB_kernel(
    const float* __restrict__ vtmp, const float* __restrict__ ssbuf,
    float* __restrict__ out)
{
  const int b    = blockIdx.x;
  const int tid  = threadIdx.x;
  const int d    = tid & 255;
  const int kq   = tid >> 8;
  const int lane = tid & 63;
  const int w    = tid >> 6;

  __shared__ float redB[16];
  __shared__ float gsh;

  float u[4];
  float p2 = 0.f;
#pragma unroll
  for (int kk = 0; kk < 4; ++kk) {
    const int k = kq * 4 + kk;
    const float rk = 1.0f / fmaxf(sqrtf(ssbuf[b * KK + k]), FEPS);
    u[kk] = vtmp[((size_t)b * KK + k) * DD + d] * rk;
    p2 += u[kk] * u[kk];
  }
#pragma unroll
  for (int off = 32; off >= 1; off >>= 1) p2 += __shfl_xor(p2, off);
  if (lane == 0) redB[w] = p2;
  __syncthreads();

  if (tid == 0) {
    float g = 0.f;
#pragma unroll
    for (int i = 0; i < 16; ++i) g += redB[i];
    gsh = 1.0f / fmaxf(sqrtf(g), FEPS);
  }
  __syncthreads();

  const float g = gsh;
#pragma unroll
  for (int kk = 0; kk < 4; ++kk) {
    const int k = kq * 4 + kk;
    out[(size_t)b * KK * DD + k * DD + d] = u[kk] * g;
  }
}

extern "C" void kernel_launch(void* const* d_in, const int* in_sizes, int n_in,
                              void* d_out, int out_size, void* d_ws, size_t ws_size,
                              hipStream_t stream) {
  const float* x    = (const float*)d_in[0];
  const int*   mask = (const int*)d_in[1];
  const float* W    = (const float*)d_in[2];
  const float* bias = (const float*)d_in[3];
  const float* cent = (const float*)d_in[4];
  float* out = (float*)d_out;

  const size_t pvN   = (size_t)TILES * KK * DD;
  const size_t psN   = (size_t)TILES * KK;
  const size_t vtmpN = (size_t)BB * KK * DD;
  const size_t ssN   = (size_t)BB * KK;
  const size_t clN   = (size_t)BB * NN;     // clist ints
  const size_t ccN   = (size_t)BB;          // ccount ints

  const size_t needP = (pvN + psN + vtmpN + ssN) * sizeof(float)
                     + (clN + ccN) * sizeof(int);

  if (ws_size >= needP) {
    float* pv    = (float*)d_ws;
    float* ps    = pv + pvN;
    float* vtmp  = ps + psN;
    float* ssbuf = vtmp + vtmpN;
    int*   clist = (int*)(ssbuf + ssN);
    int*   ccnt  = clist + clN;
    compact_kernel<<<BB, 1024, 0, stream>>>(mask, clist, ccnt);
    fused_kernel<<<TILES, 256, 0, stream>>>(x, clist, ccnt, W, bias, pv, ps, 1);
    finalizeA_kernel<<<BB * KK, 256, 0, stream>>>(pv, ps, cent, vtmp, ssbuf, ccnt, 0);
    finalizeB_kernel<<<BB, 1024, 0, stream>>>(vtmp, ssbuf, out);
  } else {
    float* vacc  = (float*)d_ws;              // [BB][KK][DD]
    float* sacc  = vacc + vtmpN;              // [BB][KK]
    float* vtmp  = sacc + ssN;
    float* ssbuf = vtmp + vtmpN;
    int*   clist = (int*)(ssbuf + ssN);
    int*   ccnt  = clist + clN;
    hipMemsetAsync(d_ws, 0, (vtmpN + ssN) * sizeof(float), stream);
    compact_kernel<<<BB, 1024, 0, stream>>>(mask, clist, ccnt);
    fused_kernel<<<TILES, 256, 0, stream>>>(x, clist, ccnt, W, bias, vacc, sacc, 0);
    finalizeA_kernel<<<BB * KK, 256, 0, stream>>>(vacc, sacc, cent, vtmp, ssbuf, nullptr, 1);
    finalizeB_kernel<<<BB, 1024, 0, stream>>>(vtmp, ssbuf, out);
  }
}

// Round 17
// 67.406 us; speedup vs baseline: 1.0790x; 1.0044x over previous
//
#include <hip/hip_runtime.h>
#include <cstdint>
#include <cstddef>

#define BB 32
#define NN 4096
#define DD 256
#define KK 16

constexpr float FEPS = 1e-12f;

__device__ __forceinline__ float dot4(float4 a, float4 b) {
  return a.x*b.x + a.y*b.y + a.z*b.z + a.w*b.w;
}
__device__ __forceinline__ float4 f4add(float4 a, float4 b) {
  return make_float4(a.x+b.x, a.y+b.y, a.z+b.z, a.w+b.w);
}
__device__ __forceinline__ float4 f4fma(float s, float4 x, float4 a) {
  a.x += s*x.x; a.y += s*x.y; a.z += s*x.z; a.w += s*x.w; return a;
}

// ---------------------------------------------------------------------------
// Fused kernel (r14 structure: per-tile compaction): TILE tokens per block,
// 256 threads, 8 blk/CU (TILE=64).
// Compaction: ballot over the 64 token masks -> cmap[slot]=orig token, cnt.
// Phase A: thread = (slot, k-group); staged 16-dim LDS chunks (dbuf, pad4->5).
// Phase B: wave = k-quad over cnt compacted tokens; row index via
//          __shfl(creg, tt) (register broadcast) instead of per-iter LDS read.
// ---------------------------------------------------------------------------
template <int TILE>
__global__ __launch_bounds__(256, (TILE == 64 ? 8 : 4)) void fused_kernel(
    const float* __restrict__ x, const int* __restrict__ mask,
    const float* __restrict__ W, const float* __restrict__ bias,
    float* __restrict__ outv, float* __restrict__ outs, int partial_mode)
{
  constexpr int NG    = 256 / TILE;     // k-groups (thread layers)
  constexpr int KPT   = KK / NG;        // k per thread in Phase A
  constexpr int SW4   = TILE / 64;      // staging float4s per thread per chunk
  constexpr int WPG   = 4 / NG;         // waves per k-group
  constexpr int TPBAT = NN / TILE;

  __shared__ float4 xs4[2][TILE * 5];   // 2 x 5*TILE float4 (pad 4->5)
  __shared__ float  al[TILE * KK];
  __shared__ float  psum[TILE][NG];
  __shared__ float  asacc[WPG][KK];
  __shared__ int    cmap[TILE];         // compacted slot -> original token

  const int tid  = threadIdx.x;
  const int lane = tid & 63;
  const int wave = tid >> 6;
  const int tok  = tid & (TILE - 1);    // Phase-A slot (compacted index)
  const int kg   = __builtin_amdgcn_readfirstlane(tid / TILE);
  const int slot = __builtin_amdgcn_readfirstlane(wave & (WPG - 1));

  const int tile = blockIdx.x;
  const int b    = tile / TPBAT;
  const int n0   = (tile % TPBAT) * TILE;

  const float4* xb4 = reinterpret_cast<const float4*>(x + ((size_t)b*NN + n0)*DD);
  const int*    mb  = mask + (size_t)b*NN + n0;

  // ---------------- compaction (TILE==64): ballot -> cmap, cnt ------------
  int cnt;
  if constexpr (TILE == 64) {
    const int m = mb[lane];                       // lane = original token
    const unsigned long long bits = __ballot(m != 0);
    cnt = __builtin_amdgcn_readfirstlane((int)__popcll(bits));
    if (wave == 0 && m) {
      const unsigned long long below = bits & ((1ull << lane) - 1ull);
      cmap[(int)__popcll(below)] = lane;
    }
  } else {
    cnt = TILE;
    if (tid < TILE) cmap[tid] = tid;
  }
  __syncthreads();                                // cmap visible

  // each lane holds its slot's row in a register (for shfl-broadcast later)
  int creg;
  if constexpr (TILE == 64) creg = cmap[lane];

  // ---------------- Phase A: KPT logits per thread, dbuf staging ----------
  float part[KPT];
#pragma unroll
  for (int q = 0; q < KPT; ++q) part[q] = bias[kg * KPT + q];

  const int st = tid >> 2;              // staging slot (0..63)
  const int sj = tid & 3;               // staging float4 col within chunk

  int srow[SW4], sact[SW4];
#pragma unroll
  for (int l = 0; l < SW4; ++l) {
    const int sl = st + l * 64;
    sact[l] = sl < cnt;
    srow[l] = sact[l] ? cmap[sl] : 0;
  }

  // prologue: stage chunk 0 into buffer 0 (active slots only)
#pragma unroll
  for (int l = 0; l < SW4; ++l) {
    if (sact[l]) {
      const float4 p0 = xb4[(size_t)srow[l] * 64 + sj];
      xs4[0][(st + l * 64) * 5 + sj] = p0;
    }
  }

#pragma unroll 1
  for (int c = 0; c < 16; ++c) {        // 16 chunks of 16 dims
    __syncthreads();
    const int cur = c & 1;

    float4 nxt[SW4];
    if (c < 15) {
#pragma unroll
      for (int l = 0; l < SW4; ++l)
        if (sact[l])
          nxt[l] = xb4[(size_t)srow[l] * 64 + (c + 1) * 4 + sj];
    }

#pragma unroll
    for (int j = 0; j < 4; ++j) {
      const float4 xv = xs4[cur][tok * 5 + j];
      const float* Wc = W + c * 16 + j * 4;
#pragma unroll
      for (int q = 0; q < KPT; ++q) {
        const float4 wv = *reinterpret_cast<const float4*>(Wc + (kg * KPT + q) * DD);
        part[q] += dot4(xv, wv);
      }
    }

    if (c < 15) {
#pragma unroll
      for (int l = 0; l < SW4; ++l)
        if (sact[l])
          xs4[cur ^ 1][(st + l * 64) * 5 + sj] = nxt[l];
    }
  }

  // active predicate for this slot
  int act;
  if constexpr (TILE == 64) act = (tok < cnt);
  else                      act = mb[tok];

  // masked softmax across NG thread-layers via psum exchange
  float e[KPT], pexp = 0.f;
#pragma unroll
  for (int q = 0; q < KPT; ++q) {
    const float ev = __expf(part[q]);
    e[q] = act ? ev : 0.0f;             // zero garbage slots
    pexp += e[q];
  }
  psum[tok][kg] = pexp;
  __syncthreads();
  float a[KPT];
  {
    float denom = 0.f;
#pragma unroll
    for (int g = 0; g < NG; ++g) denom += psum[tok][g];
    const float r = act ? (1.0f / denom) : 0.0f;
#pragma unroll
    for (int q = 0; q < KPT; ++q) a[q] = e[q] * r;
#pragma unroll
    for (int q4 = 0; q4 < KPT; q4 += 4)
      *reinterpret_cast<float4*>(&al[tok * KK + kg * KPT + q4]) =
          make_float4(a[q4], a[q4+1], a[q4+2], a[q4+3]);
  }

  // asum: butterfly over 64 lanes (zeros for inactive slots)
  {
    float red[KPT];
#pragma unroll
    for (int q = 0; q < KPT; ++q) red[q] = a[q];
#pragma unroll
    for (int off = 32; off >= 1; off >>= 1)
#pragma unroll
      for (int q = 0; q < KPT; ++q) red[q] += __shfl_xor(red[q], off);
    if (lane == 0)
#pragma unroll
      for (int q = 0; q < KPT; ++q) asacc[slot][kg * KPT + q] = red[q];
  }
  __syncthreads();

  // ------ Phase B: wave = k-quad, sweep the cnt compacted tokens ----------
  float4 acc0 = make_float4(0.f,0.f,0.f,0.f);
  float4 acc1 = make_float4(0.f,0.f,0.f,0.f);
  float4 acc2 = make_float4(0.f,0.f,0.f,0.f);
  float4 acc3 = make_float4(0.f,0.f,0.f,0.f);

  const float4* xw = xb4 + lane;        // lane owns dims 4*lane..4*lane+3
  const int kq4 = 4 * wave;             // this wave's k-quad offset in al row

#pragma unroll 4
  for (int tt = 0; tt < cnt; ++tt) {
    int tr;
    if constexpr (TILE == 64) tr = __shfl(creg, tt);   // reg broadcast
    else                      tr = cmap[tt];
    const float4 xv = xw[(size_t)tr * 64];
    const float4 av = *reinterpret_cast<const float4*>(&al[tt * KK + kq4]);
    acc0 = f4fma(av.x, xv, acc0);
    acc1 = f4fma(av.y, xv, acc1);
    acc2 = f4fma(av.z, xv, acc2);
    acc3 = f4fma(av.w, xv, acc3);
  }

  // ------------- output ----------------------------------------------------
  const int kq = wave * 4;
  if (partial_mode) {
    float4* dst = reinterpret_cast<float4*>(outv + (size_t)tile * KK * DD);
    dst[(kq + 0) * 64 + lane] = acc0;
    dst[(kq + 1) * 64 + lane] = acc1;
    dst[(kq + 2) * 64 + lane] = acc2;
    dst[(kq + 3) * 64 + lane] = acc3;
    if (tid < KK) {
      float s = 0.f;
#pragma unroll
      for (int sl = 0; sl < WPG; ++sl) s += asacc[sl][tid];
      outs[tile * KK + tid] = s;
    }
  } else {
    float* vb = outv + (size_t)b * KK * DD;
    const float4 aa4[4] = {acc0, acc1, acc2, acc3};
#pragma unroll
    for (int i = 0; i < 4; ++i) {
      float* p = vb + (kq + i) * DD + 4 * lane;
      atomicAdd(p + 0, aa4[i].x);
      atomicAdd(p + 1, aa4[i].y);
      atomicAdd(p + 2, aa4[i].z);
      atomicAdd(p + 3, aa4[i].w);
    }
    if (tid < KK) {
      float s = 0.f;
#pragma unroll
      for (int sl = 0; sl < WPG; ++sl) s += asacc[sl][tid];
      atomicAdd(&outs[b * KK + tid], s);
    }
  }
}

// ---------------------------------------------------------------------------
// Finalize A (BB*KK blocks x 256 thr): block = (b,k). float4 slice-sum with
// 4 slice-groups x 4 accumulators, LDS combine, ssum by wave butterfly.
// ---------------------------------------------------------------------------
__global__ __launch_bounds__(256) void finalizeA_kernel(
    const float* __restrict__ pv, const float* __restrict__ ps,
    const float* __restrict__ cent, float* __restrict__ vtmp,
    float* __restrict__ ssbuf, int nslice)
{
  const int blk = blockIdx.x;
  const int b   = blk >> 4;
  const int k   = blk & 15;
  const int tid = threadIdx.x;
  const int sg  = tid >> 6;           // slice group 0..3
  const int ld  = tid & 63;           // float4 dim index

  __shared__ float4 cmbA[3][64];

  float pval = 0.f;
  for (int s = ld; s < nslice; s += 64)
    pval += ps[(size_t)(b * nslice + s) * KK + k];
#pragma unroll
  for (int off = 32; off >= 1; off >>= 1) pval += __shfl_xor(pval, off);
  const float ssum = pval;

  const float4* pv4 = reinterpret_cast<const float4*>(pv);
  const size_t base = ((size_t)b * nslice * KK + k) * 64 + ld;
  float4 a0 = make_float4(0.f,0.f,0.f,0.f), a1 = a0, a2 = a0, a3 = a0;
  int s = sg;
  for (; s + 12 < nslice; s += 16) {
    a0 = f4add(a0, pv4[base + (size_t)(s     ) * (KK * 64)]);
    a1 = f4add(a1, pv4[base + (size_t)(s +  4) * (KK * 64)]);
    a2 = f4add(a2, pv4[base + (size_t)(s +  8) * (KK * 64)]);
    a3 = f4add(a3, pv4[base + (size_t)(s + 12) * (KK * 64)]);
  }
  for (; s < nslice; s += 4)
    a0 = f4add(a0, pv4[base + (size_t)s * (KK * 64)]);
  float4 tot = f4add(f4add(a0, a1), f4add(a2, a3));

  if (sg > 0) cmbA[sg - 1][ld] = tot;
  __syncthreads();

  if (sg == 0) {
    tot = f4add(tot, f4add(cmbA[0][ld], f4add(cmbA[1][ld], cmbA[2][ld])));
    const float4 cv = reinterpret_cast<const float4*>(cent)[k * 64 + ld];
    float4 v;
    v.x = tot.x - ssum * cv.x;
    v.y = tot.y - ssum * cv.y;
    v.z = tot.z - ssum * cv.z;
    v.w = tot.w - ssum * cv.w;
    reinterpret_cast<float4*>(vtmp)[((size_t)b * KK + k) * 64 + ld] = v;
    float p = dot4(v, v);
#pragma unroll
    for (int off = 32; off >= 1; off >>= 1) p += __shfl_xor(p, off);
    if (ld == 0) ssbuf[blk] = p;
  }
}

// ---------------------------------------------------------------------------
// Finalize B (BB blocks x 1024 thr): intra-cluster + global L2 normalize.
// ---------------------------------------------------------------------------
__global__ __launch_bounds__(1024) void finalizeB_kernel(
    const float* __restrict__ vtmp, const float* __restrict__ ssbuf,
    float* __restrict__ out)
{
  const int b    = blockIdx.x;
  const int tid  = threadIdx.x;
  const int d    = tid & 255;
  const int kq   = tid >> 8;
  const int lane = tid & 63;
  const int w    = tid >> 6;

  __shared__ float redB[16];
  __shared__ float gsh;

  float u[4];
  float p2 = 0.f;
#pragma unroll
  for (int kk = 0; kk < 4; ++kk) {
    const int k = kq * 4 + kk;
    const float rk = 1.0f / fmaxf(sqrtf(ssbuf[b * KK + k]), FEPS);
    u[kk] = vtmp[((size_t)b * KK + k) * DD + d] * rk;
    p2 += u[kk] * u[kk];
  }
#pragma unroll
  for (int off = 32; off >= 1; off >>= 1) p2 += __shfl_xor(p2, off);
  if (lane == 0) redB[w] = p2;
  __syncthreads();

  if (tid == 0) {
    float g = 0.f;
#pragma unroll
    for (int i = 0; i < 16; ++i) g += redB[i];
    gsh = 1.0f / fmaxf(sqrtf(g), FEPS);
  }
  __syncthreads();

  const float g = gsh;
#pragma unroll
  for (int kk = 0; kk < 4; ++kk) {
    const int k = kq * 4 + kk;
    out[(size_t)b * KK * DD + k * DD + d] = u[kk] * g;
  }
}

extern "C" void kernel_launch(void* const* d_in, const int* in_sizes, int n_in,
                              void* d_out, int out_size, void* d_ws, size_t ws_size,
                              hipStream_t stream) {
  const float* x    = (const float*)d_in[0];
  const int*   mask = (const int*)d_in[1];
  const float* W    = (const float*)d_in[2];
  const float* bias = (const float*)d_in[3];
  const float* cent = (const float*)d_in[4];
  float* out = (float*)d_out;

  const size_t vtmpN = (size_t)BB * KK * DD;
  const size_t ssN   = (size_t)BB * KK;

  const size_t t64   = (size_t)BB * (NN / 64);    // 2048 tiles
  const size_t t128  = (size_t)BB * (NN / 128);   // 1024 tiles
  const size_t need64  = (t64  * KK * DD + t64  * KK + vtmpN + ssN) * sizeof(float);
  const size_t need128 = (t128 * KK * DD + t128 * KK + vtmpN + ssN) * sizeof(float);

  if (ws_size >= need64) {
    float* pv    = (float*)d_ws;
    float* ps    = pv + t64 * KK * DD;
    float* vtmp  = ps + t64 * KK;
    float* ssbuf = vtmp + vtmpN;
    fused_kernel<64><<<(int)t64, 256, 0, stream>>>(x, mask, W, bias, pv, ps, 1);
    finalizeA_kernel<<<BB * KK, 256, 0, stream>>>(pv, ps, cent, vtmp, ssbuf, NN / 64);
    finalizeB_kernel<<<BB, 1024, 0, stream>>>(vtmp, ssbuf, out);
  } else if (ws_size >= need128) {
    float* pv    = (float*)d_ws;
    float* ps    = pv + t128 * KK * DD;
    float* vtmp  = ps + t128 * KK;
    float* ssbuf = vtmp + vtmpN;
    fused_kernel<128><<<(int)t128, 256, 0, stream>>>(x, mask, W, bias, pv, ps, 1);
    finalizeA_kernel<<<BB * KK, 256, 0, stream>>>(pv, ps, cent, vtmp, ssbuf, NN / 128);
    finalizeB_kernel<<<BB, 1024, 0, stream>>>(vtmp, ssbuf, out);
  } else {
    float* vacc  = (float*)d_ws;                 // [BB][KK][DD]
    float* sacc  = vacc + vtmpN;                 // [BB][KK]
    float* vtmp  = sacc + ssN;
    float* ssbuf = vtmp + vtmpN;
    hipMemsetAsync(d_ws, 0, (vtmpN + ssN) * sizeof(float), stream);
    fused_kernel<64><<<(int)t64, 256, 0, stream>>>(x, mask, W, bias, vacc, sacc, 0);
    finalizeA_kernel<<<BB * KK, 256, 0, stream>>>(vacc, sacc, cent, vtmp, ssbuf, 1);
    finalizeB_kernel<<<BB, 1024, 0, stream>>>(vtmp, ssbuf, out);
  }
}

// Round 18
// 58.411 us; speedup vs baseline: 1.2451x; 1.1540x over previous
//
#include <hip/hip_runtime.h>
#include <cstdint>
#include <cstddef>

#define BB 32
#define NN 4096
#define DD 256
#define KK 16

constexpr float FEPS = 1e-12f;

__device__ __forceinline__ float dot4(float4 a, float4 b) {
  return a.x*b.x + a.y*b.y + a.z*b.z + a.w*b.w;
}
__device__ __forceinline__ float4 f4add(float4 a, float4 b) {
  return make_float4(a.x+b.x, a.y+b.y, a.z+b.z, a.w+b.w);
}
__device__ __forceinline__ float4 f4fma(float s, float4 x, float4 a) {
  a.x += s*x.x; a.y += s*x.y; a.z += s*x.z; a.w += s*x.w; return a;
}

// ---------------------------------------------------------------------------
// Fused kernel (r14 exact: per-tile compaction): TILE tokens per block,
// 256 threads, 8 blk/CU (TILE=64).
// Compaction: ballot over the 64 token masks -> cmap[slot]=orig token, cnt.
// Only unmasked rows are staged / processed (slots >= cnt hold garbage and
// are exactly zeroed through the softmax predicates).
// Phase A: thread = (slot, k-group); staged 16-dim LDS chunks (dbuf, pad4->5).
// Phase B: wave = k-quad over cnt compacted tokens, x re-read via L1/L2.
// ---------------------------------------------------------------------------
template <int TILE>
__global__ __launch_bounds__(256, (TILE == 64 ? 8 : 4)) void fused_kernel(
    const float* __restrict__ x, const int* __restrict__ mask,
    const float* __restrict__ W, const float* __restrict__ bias,
    float* __restrict__ outv, float* __restrict__ outs, int partial_mode)
{
  constexpr int NG    = 256 / TILE;     // k-groups (thread layers)
  constexpr int KPT   = KK / NG;        // k per thread in Phase A
  constexpr int SW4   = TILE / 64;      // staging float4s per thread per chunk
  constexpr int WPG   = 4 / NG;         // waves per k-group
  constexpr int TPBAT = NN / TILE;

  __shared__ float4 xs4[2][TILE * 5];   // 2 x 5*TILE float4 (pad 4->5)
  __shared__ float  al[TILE * KK];
  __shared__ float  psum[TILE][NG];
  __shared__ float  asacc[WPG][KK];
  __shared__ int    cmap[TILE];         // compacted slot -> original token

  const int tid  = threadIdx.x;
  const int lane = tid & 63;
  const int wave = tid >> 6;
  const int tok  = tid & (TILE - 1);    // Phase-A slot (compacted index)
  const int kg   = __builtin_amdgcn_readfirstlane(tid / TILE);
  const int slot = __builtin_amdgcn_readfirstlane(wave & (WPG - 1));

  const int tile = blockIdx.x;
  const int b    = tile / TPBAT;
  const int n0   = (tile % TPBAT) * TILE;

  const float4* xb4 = reinterpret_cast<const float4*>(x + ((size_t)b*NN + n0)*DD);
  const int*    mb  = mask + (size_t)b*NN + n0;

  // ---------------- compaction (TILE==64): ballot -> cmap, cnt ------------
  int cnt;
  if constexpr (TILE == 64) {
    const int m = mb[lane];                       // lane = original token
    const unsigned long long bits = __ballot(m != 0);
    cnt = __builtin_amdgcn_readfirstlane((int)__popcll(bits));
    if (wave == 0 && m) {
      const unsigned long long below = bits & ((1ull << lane) - 1ull);
      cmap[(int)__popcll(below)] = lane;
    }
  } else {
    cnt = TILE;
    if (tid < TILE) cmap[tid] = tid;
  }
  __syncthreads();                                // cmap visible

  // ---------------- Phase A: KPT logits per thread, dbuf staging ----------
  float part[KPT];
#pragma unroll
  for (int q = 0; q < KPT; ++q) part[q] = bias[kg * KPT + q];

  const int st = tid >> 2;              // staging slot (0..63)
  const int sj = tid & 3;               // staging float4 col within chunk

  int srow[SW4], sact[SW4];
#pragma unroll
  for (int l = 0; l < SW4; ++l) {
    const int sl = st + l * 64;
    sact[l] = sl < cnt;
    srow[l] = sact[l] ? cmap[sl] : 0;
  }

  // prologue: stage chunk 0 into buffer 0 (active slots only)
#pragma unroll
  for (int l = 0; l < SW4; ++l) {
    if (sact[l]) {
      const float4 p0 = xb4[(size_t)srow[l] * 64 + sj];
      xs4[0][(st + l * 64) * 5 + sj] = p0;
    }
  }

#pragma unroll 1
  for (int c = 0; c < 16; ++c) {        // 16 chunks of 16 dims
    __syncthreads();
    const int cur = c & 1;

    float4 nxt[SW4];
    if (c < 15) {
#pragma unroll
      for (int l = 0; l < SW4; ++l)
        if (sact[l])
          nxt[l] = xb4[(size_t)srow[l] * 64 + (c + 1) * 4 + sj];
    }

#pragma unroll
    for (int j = 0; j < 4; ++j) {
      const float4 xv = xs4[cur][tok * 5 + j];
      const float* Wc = W + c * 16 + j * 4;
#pragma unroll
      for (int q = 0; q < KPT; ++q) {
        const float4 wv = *reinterpret_cast<const float4*>(Wc + (kg * KPT + q) * DD);
        part[q] += dot4(xv, wv);
      }
    }

    if (c < 15) {
#pragma unroll
      for (int l = 0; l < SW4; ++l)
        if (sact[l])
          xs4[cur ^ 1][(st + l * 64) * 5 + sj] = nxt[l];
    }
  }

  // active predicate for this slot
  int act;
  if constexpr (TILE == 64) act = (tok < cnt);
  else                      act = mb[tok];

  // masked softmax across NG thread-layers via psum exchange
  float e[KPT], pexp = 0.f;
#pragma unroll
  for (int q = 0; q < KPT; ++q) {
    const float ev = __expf(part[q]);
    e[q] = act ? ev : 0.0f;             // zero garbage slots
    pexp += e[q];
  }
  psum[tok][kg] = pexp;
  __syncthreads();
  float a[KPT];
  {
    float denom = 0.f;
#pragma unroll
    for (int g = 0; g < NG; ++g) denom += psum[tok][g];
    const float r = act ? (1.0f / denom) : 0.0f;
#pragma unroll
    for (int q = 0; q < KPT; ++q) a[q] = e[q] * r;
#pragma unroll
    for (int q4 = 0; q4 < KPT; q4 += 4)
      *reinterpret_cast<float4*>(&al[tok * KK + kg * KPT + q4]) =
          make_float4(a[q4], a[q4+1], a[q4+2], a[q4+3]);
  }

  // asum: butterfly over 64 lanes (zeros for inactive slots)
  {
    float red[KPT];
#pragma unroll
    for (int q = 0; q < KPT; ++q) red[q] = a[q];
#pragma unroll
    for (int off = 32; off >= 1; off >>= 1)
#pragma unroll
      for (int q = 0; q < KPT; ++q) red[q] += __shfl_xor(red[q], off);
    if (lane == 0)
#pragma unroll
      for (int q = 0; q < KPT; ++q) asacc[slot][kg * KPT + q] = red[q];
  }
  __syncthreads();

  // ------ Phase B: wave = k-quad, sweep the cnt compacted tokens ----------
  float4 acc0 = make_float4(0.f,0.f,0.f,0.f);
  float4 acc1 = make_float4(0.f,0.f,0.f,0.f);
  float4 acc2 = make_float4(0.f,0.f,0.f,0.f);
  float4 acc3 = make_float4(0.f,0.f,0.f,0.f);

  const float4* xw = xb4 + lane;        // lane owns dims 4*lane..4*lane+3
  const int kq4 = 4 * wave;             // this wave's k-quad offset in al row

#pragma unroll 4
  for (int tt = 0; tt < cnt; ++tt) {
    const int tr = cmap[tt];
    const float4 xv = xw[(size_t)tr * 64];
    const float4 av = *reinterpret_cast<const float4*>(&al[tt * KK + kq4]);
    acc0 = f4fma(av.x, xv, acc0);
    acc1 = f4fma(av.y, xv, acc1);
    acc2 = f4fma(av.z, xv, acc2);
    acc3 = f4fma(av.w, xv, acc3);
  }

  // ------------- output ----------------------------------------------------
  const int kq = wave * 4;
  if (partial_mode) {
    float4* dst = reinterpret_cast<float4*>(outv + (size_t)tile * KK * DD);
    dst[(kq + 0) * 64 + lane] = acc0;
    dst[(kq + 1) * 64 + lane] = acc1;
    dst[(kq + 2) * 64 + lane] = acc2;
    dst[(kq + 3) * 64 + lane] = acc3;
    if (tid < KK) {
      float s = 0.f;
#pragma unroll
      for (int sl = 0; sl < WPG; ++sl) s += asacc[sl][tid];
      outs[tile * KK + tid] = s;
    }
  } else {
    float* vb = outv + (size_t)b * KK * DD;
    const float4 aa4[4] = {acc0, acc1, acc2, acc3};
#pragma unroll
    for (int i = 0; i < 4; ++i) {
      float* p = vb + (kq + i) * DD + 4 * lane;
      atomicAdd(p + 0, aa4[i].x);
      atomicAdd(p + 1, aa4[i].y);
      atomicAdd(p + 2, aa4[i].z);
      atomicAdd(p + 3, aa4[i].w);
    }
    if (tid < KK) {
      float s = 0.f;
#pragma unroll
      for (int sl = 0; sl < WPG; ++sl) s += asacc[sl][tid];
      atomicAdd(&outs[b * KK + tid], s);
    }
  }
}

// ---------------------------------------------------------------------------
// Finalize A (BB*KK blocks x 256 thr): block = (b,k). float4 slice-sum with
// 4 slice-groups x 4 accumulators, LDS combine, ssum by wave butterfly.
// ---------------------------------------------------------------------------
__global__ __launch_bounds__(256) void finalizeA_kernel(
    const float* __restrict__ pv, const float* __restrict__ ps,
    const float* __restrict__ cent, float* __restrict__ vtmp,
    float* __restrict__ ssbuf, int nslice)
{
  const int blk = blockIdx.x;
  const int b   = blk >> 4;
  const int k   = blk & 15;
  const int tid = threadIdx.x;
  const int sg  = tid >> 6;           // slice group 0..3
  const int ld  = tid & 63;           // float4 dim index

  __shared__ float4 cmbA[3][64];

  float pval = 0.f;
  for (int s = ld; s < nslice; s += 64)
    pval += ps[(size_t)(b * nslice + s) * KK + k];
#pragma unroll
  for (int off = 32; off >= 1; off >>= 1) pval += __shfl_xor(pval, off);
  const float ssum = pval;

  const float4* pv4 = reinterpret_cast<const float4*>(pv);
  const size_t base = ((size_t)b * nslice * KK + k) * 64 + ld;
  float4 a0 = make_float4(0.f,0.f,0.f,0.f), a1 = a0, a2 = a0, a3 = a0;
  int s = sg;
  for (; s + 12 < nslice; s += 16) {
    a0 = f4add(a0, pv4[base + (size_t)(s     ) * (KK * 64)]);
    a1 = f4add(a1, pv4[base + (size_t)(s +  4) * (KK * 64)]);
    a2 = f4add(a2, pv4[base + (size_t)(s +  8) * (KK * 64)]);
    a3 = f4add(a3, pv4[base + (size_t)(s + 12) * (KK * 64)]);
  }
  for (; s < nslice; s += 4)
    a0 = f4add(a0, pv4[base + (size_t)s * (KK * 64)]);
  float4 tot = f4add(f4add(a0, a1), f4add(a2, a3));

  if (sg > 0) cmbA[sg - 1][ld] = tot;
  __syncthreads();

  if (sg == 0) {
    tot = f4add(tot, f4add(cmbA[0][ld], f4add(cmbA[1][ld], cmbA[2][ld])));
    const float4 cv = reinterpret_cast<const float4*>(cent)[k * 64 + ld];
    float4 v;
    v.x = tot.x - ssum * cv.x;
    v.y = tot.y - ssum * cv.y;
    v.z = tot.z - ssum * cv.z;
    v.w = tot.w - ssum * cv.w;
    reinterpret_cast<float4*>(vtmp)[((size_t)b * KK + k) * 64 + ld] = v;
    float p = dot4(v, v);
#pragma unroll
    for (int off = 32; off >= 1; off >>= 1) p += __shfl_xor(p, off);
    if (ld == 0) ssbuf[blk] = p;
  }
}

// ---------------------------------------------------------------------------
// Finalize B (BB blocks x 1024 thr): intra-cluster + global L2 normalize.
// ---------------------------------------------------------------------------
__global__ __launch_bounds__(1024) void finalizeB_kernel(
    const float* __restrict__ vtmp, const float* __restrict__ ssbuf,
    float* __restrict__ out)
{
  const int b    = blockIdx.x;
  const int tid  = threadIdx.x;
  const int d    = tid & 255;
  const int kq   = tid >> 8;
  const int lane = tid & 63;
  const int w    = tid >> 6;

  __shared__ float redB[16];
  __shared__ float gsh;

  float u[4];
  float p2 = 0.f;
#pragma unroll
  for (int kk = 0; kk < 4; ++kk) {
    const int k = kq * 4 + kk;
    const float rk = 1.0f / fmaxf(sqrtf(ssbuf[b * KK + k]), FEPS);
    u[kk] = vtmp[((size_t)b * KK + k) * DD + d] * rk;
    p2 += u[kk] * u[kk];
  }
#pragma unroll
  for (int off = 32; off >= 1; off >>= 1) p2 += __shfl_xor(p2, off);
  if (lane == 0) redB[w] = p2;
  __syncthreads();

  if (tid == 0) {
    float g = 0.f;
#pragma unroll
    for (int i = 0; i < 16; ++i) g += redB[i];
    gsh = 1.0f / fmaxf(sqrtf(g), FEPS);
  }
  __syncthreads();

  const float g = gsh;
#pragma unroll
  for (int kk = 0; kk < 4; ++kk) {
    const int k = kq * 4 + kk;
    out[(size_t)b * KK * DD + k * DD + d] = u[kk] * g;
  }
}

extern "C" void kernel_launch(void* const* d_in, const int* in_sizes, int n_in,
                              void* d_out, int out_size, void* d_ws, size_t ws_size,
                              hipStream_t stream) {
  const float* x    = (const float*)d_in[0];
  const int*   mask = (const int*)d_in[1];
  const float* W    = (const float*)d_in[2];
  const float* bias = (const float*)d_in[3];
  const float* cent = (const float*)d_in[4];
  float* out = (float*)d_out;

  const size_t vtmpN = (size_t)BB * KK * DD;
  const size_t ssN   = (size_t)BB * KK;

  const size_t t64   = (size_t)BB * (NN / 64);    // 2048 tiles
  const size_t t128  = (size_t)BB * (NN / 128);   // 1024 tiles
  const size_t need64  = (t64  * KK * DD + t64  * KK + vtmpN + ssN) * sizeof(float);
  const size_t need128 = (t128 * KK * DD + t128 * KK + vtmpN + ssN) * sizeof(float);

  if (ws_size >= need64) {
    float* pv    = (float*)d_ws;
    float* ps    = pv + t64 * KK * DD;
    float* vtmp  = ps + t64 * KK;
    float* ssbuf = vtmp + vtmpN;
    fused_kernel<64><<<(int)t64, 256, 0, stream>>>(x, mask, W, bias, pv, ps, 1);
    finalizeA_kernel<<<BB * KK, 256, 0, stream>>>(pv, ps, cent, vtmp, ssbuf, NN / 64);
    finalizeB_kernel<<<BB, 1024, 0, stream>>>(vtmp, ssbuf, out);
  } else if (ws_size >= need128) {
    float* pv    = (float*)d_ws;
    float* ps    = pv + t128 * KK * DD;
    float* vtmp  = ps + t128 * KK;
    float* ssbuf = vtmp + vtmpN;
    fused_kernel<128><<<(int)t128, 256, 0, stream>>>(x, mask, W, bias, pv, ps, 1);
    finalizeA_kernel<<<BB * KK, 256, 0, stream>>>(pv, ps, cent, vtmp, ssbuf, NN / 128);
    finalizeB_kernel<<<BB, 1024, 0, stream>>>(vtmp, ssbuf, out);
  } else {
    float* vacc  = (float*)d_ws;                 // [BB][KK][DD]
    float* sacc  = vacc + vtmpN;                 // [BB][KK]
    float* vtmp  = sacc + ssN;
    float* ssbuf = vtmp + vtmpN;
    hipMemsetAsync(d_ws, 0, (vtmpN + ssN) * sizeof(float), stream);
    fused_kernel<64><<<(int)t64, 256, 0, stream>>>(x, mask, W, bias, vacc, sacc, 0);
    finalizeA_kernel<<<BB * KK, 256, 0, stream>>>(vacc, sacc, cent, vtmp, ssbuf, 1);
    finalizeB_kernel<<<BB, 1024, 0, stream>>>(vtmp, ssbuf, out);
  }
}